// Round 1
// baseline (135.817 us; speedup 1.0000x reference)
//
#include <hip/hip_runtime.h>
#include <hip/hip_bf16.h>

// ---------------------------------------------------------------------------
// Fused causal attention head: B=4, T=4096, E=128, D=64, fp32 in/out.
// Pipeline: prep_w (W -> WT bf16) -> proj (x@W via MFMA, bf16 q/k/v in ws)
//           -> attn (flash attention, 16x16x32 bf16 MFMA, fp32 accum).
// ---------------------------------------------------------------------------

typedef __attribute__((ext_vector_type(4))) float  f32x4;
typedef __attribute__((ext_vector_type(8))) __bf16 bf16x8;
typedef __attribute__((ext_vector_type(8))) unsigned short u16x8;
typedef __attribute__((ext_vector_type(4))) unsigned short u16x4;

#define T_SEQ 4096
#define DH    64
#define EDIM  128
#define QB    64
#define KVB   64
#define KSTR  72   // K_lds row stride (u16)  -> 2-way conflict on b128 reads
#define VSTR  76   // VT_lds row stride (u16) -> b64-aligned, ~4-way on writes
#define PSTR  72   // P_lds row stride (u16)

__device__ __forceinline__ unsigned short f2bf(float f) {
    unsigned int x = __builtin_bit_cast(unsigned int, f);
    unsigned int r = x + 0x7fffu + ((x >> 16) & 1u);   // round-to-nearest-even
    return (unsigned short)(r >> 16);
}

__device__ __forceinline__ f32x4 mfma_bf16(u16x8 a, u16x8 b, f32x4 c) {
    return __builtin_amdgcn_mfma_f32_16x16x32_bf16(
        __builtin_bit_cast(bf16x8, a), __builtin_bit_cast(bf16x8, b), c, 0, 0, 0);
}

// --------------------------- prep_w: W[128][64] f32 -> WT[3][64][128] bf16 --
__global__ __launch_bounds__(256) void prep_w_kernel(
    const float* __restrict__ wq, const float* __restrict__ wk,
    const float* __restrict__ wv, unsigned short* __restrict__ wt)
{
    int o = blockIdx.x * 256 + threadIdx.x;   // grid 96 -> 24576 elems
    int m   = o >> 13;
    int rem = o & 8191;
    int d = rem >> 7, e = rem & 127;
    const float* W = (m == 0) ? wq : (m == 1) ? wk : wv;
    wt[o] = f2bf(W[e * DH + d]);
}

// --------------------------- proj: q/k/v = x @ W (q scaled by 1/8) ---------
__global__ __launch_bounds__(256) void proj_kernel(
    const float* __restrict__ x, const unsigned short* __restrict__ wt,
    unsigned short* __restrict__ qw, unsigned short* __restrict__ kw,
    unsigned short* __restrict__ vw)
{
    __shared__ unsigned short x_lds[64 * 136];   // [64 rows][128+8 pad]

    const int tid = threadIdx.x;
    const int w   = tid >> 6;
    const int l   = tid & 63;
    const int l15 = l & 15;
    const int lg  = l >> 4;
    const int row0 = blockIdx.x * 64;

    // stage x tile (fp32 -> bf16), coalesced float4 reads
    #pragma unroll
    for (int i = 0; i < 8; ++i) {
        int f4  = tid + i * 256;          // 0..2047
        int row = f4 >> 5;                // 32 float4 per row
        int c4  = (f4 & 31) * 4;
        f32x4 xv = *(const f32x4*)(x + (row0 + row) * EDIM + c4);
        u16x4 bv = { f2bf(xv[0]), f2bf(xv[1]), f2bf(xv[2]), f2bf(xv[3]) };
        *(u16x4*)&x_lds[row * 136 + c4] = bv;
    }
    __syncthreads();

    // A fragments: row = w*16 + l15, k = kt*32 + lg*8 .. +8
    u16x8 af[4];
    #pragma unroll
    for (int kt = 0; kt < 4; ++kt)
        af[kt] = *(const u16x8*)&x_lds[(w * 16 + l15) * 136 + kt * 32 + lg * 8];

    unsigned short* outs[3] = { qw, kw, vw };
    #pragma unroll
    for (int m = 0; m < 3; ++m) {
        #pragma unroll
        for (int nt = 0; nt < 4; ++nt) {
            f32x4 acc = {};
            #pragma unroll
            for (int kt = 0; kt < 4; ++kt) {
                u16x8 bfrag = *(const u16x8*)(wt + (m * 64 + nt * 16 + l15) * EDIM
                                                 + kt * 32 + lg * 8);
                acc = mfma_bf16(af[kt], bfrag, acc);
            }
            const float sc = (m == 0) ? 0.125f : 1.0f;  // fold 1/sqrt(64) into q
            #pragma unroll
            for (int r = 0; r < 4; ++r) {
                int row = row0 + w * 16 + lg * 4 + r;
                outs[m][row * DH + nt * 16 + l15] = f2bf(acc[r] * sc);
            }
        }
    }
}

// --------------------------- attn: flash attention, causal -----------------
__global__ __launch_bounds__(256) void attn_kernel(
    const unsigned short* __restrict__ qg, const unsigned short* __restrict__ kg,
    const unsigned short* __restrict__ vg, float* __restrict__ out)
{
    __shared__ unsigned short K_lds[KVB * KSTR];       // K[key][d]
    __shared__ unsigned short VT_lds[DH * VSTR];       // V^T[d][key]
    __shared__ unsigned short P_lds[4 * 16 * PSTR];    // per-wave P[qrow][key]

    const int tid = threadIdx.x;
    const int w   = tid >> 6;
    const int l   = tid & 63;
    const int l15 = l & 15;
    const int lg  = l >> 4;

    const int bid   = blockIdx.x;
    const int b     = bid >> 6;        // 64 q-tiles per batch
    const int qt    = bid & 63;
    const int qbase = qt * QB;
    const int base  = b * T_SEQ;       // batch row offset

    // Q fragments (rows w*16+l15), d = kt*32 + lg*8 .. +8
    u16x8 qf[2];
    {
        const unsigned short* qrow = qg + (base + qbase + w * 16 + l15) * DH;
        qf[0] = *(const u16x8*)(qrow +  0 + lg * 8);
        qf[1] = *(const u16x8*)(qrow + 32 + lg * 8);
    }

    f32x4 o_acc[4] = {};               // O[qrow][dt*16+l15]
    float m_run[4], l_run[4];
    #pragma unroll
    for (int r = 0; r < 4; ++r) { m_run[r] = -1e30f; l_run[r] = 0.0f; }

    const int n_tiles = qt + 1;
    for (int it = 0; it < n_tiles; ++it) {
        const int kv0 = it * KVB;

        // ---- stage K and V^T (64x64 bf16 each) ----
        #pragma unroll
        for (int i = 0; i < 4; ++i) {
            int f4  = tid + i * 256;      // 0..1023
            int row = f4 >> 4;            // 16 u16x4 per row
            int c4  = (f4 & 15) * 4;
            u16x4 kk = *(const u16x4*)(kg + (base + kv0 + row) * DH + c4);
            *(u16x4*)&K_lds[row * KSTR + c4] = kk;
            u16x4 vv = *(const u16x4*)(vg + (base + kv0 + row) * DH + c4);
            #pragma unroll
            for (int j = 0; j < 4; ++j)
                VT_lds[(c4 + j) * VSTR + row] = vv[j];
        }
        __syncthreads();

        // ---- S = Q K^T (16 x 64 per wave) ----
        f32x4 s[4];
        #pragma unroll
        for (int nt = 0; nt < 4; ++nt) {
            f32x4 acc = {};
            #pragma unroll
            for (int kt = 0; kt < 2; ++kt) {
                u16x8 kf = *(const u16x8*)&K_lds[(nt * 16 + l15) * KSTR + kt * 32 + lg * 8];
                acc = mfma_bf16(qf[kt], kf, acc);
            }
            s[nt] = acc;
        }

        // ---- causal mask (diagonal tile only) ----
        if (it == qt) {
            #pragma unroll
            for (int nt = 0; nt < 4; ++nt)
                #pragma unroll
                for (int r = 0; r < 4; ++r) {
                    int qi = qbase + w * 16 + lg * 4 + r;
                    int kj = kv0 + nt * 16 + l15;
                    if (kj > qi) s[nt][r] = -1e30f;
                }
        }

        // ---- online softmax ----
        #pragma unroll
        for (int r = 0; r < 4; ++r) {
            float m0 = fmaxf(fmaxf(s[0][r], s[1][r]), fmaxf(s[2][r], s[3][r]));
            m0 = fmaxf(m0, __shfl_xor(m0, 1));
            m0 = fmaxf(m0, __shfl_xor(m0, 2));
            m0 = fmaxf(m0, __shfl_xor(m0, 4));
            m0 = fmaxf(m0, __shfl_xor(m0, 8));

            float mnew  = fmaxf(m_run[r], m0);
            float scale = __expf(m_run[r] - mnew);
            m_run[r] = mnew;
            l_run[r] *= scale;
            #pragma unroll
            for (int dt = 0; dt < 4; ++dt) o_acc[dt][r] *= scale;

            float rs = 0.0f;
            #pragma unroll
            for (int nt = 0; nt < 4; ++nt) {
                float p0 = __expf(s[nt][r] - mnew);
                s[nt][r] = p0;
                rs += p0;
            }
            rs += __shfl_xor(rs, 1);
            rs += __shfl_xor(rs, 2);
            rs += __shfl_xor(rs, 4);
            rs += __shfl_xor(rs, 8);
            l_run[r] += rs;
        }

        // ---- P -> LDS (bf16, wave-private), reformat C-layout -> A-layout ----
        unsigned short* pw = &P_lds[w * 16 * PSTR];
        #pragma unroll
        for (int nt = 0; nt < 4; ++nt)
            #pragma unroll
            for (int r = 0; r < 4; ++r)
                pw[(lg * 4 + r) * PSTR + nt * 16 + l15] = f2bf(s[nt][r]);

        // ---- O += P V ----
        #pragma unroll
        for (int kt = 0; kt < 2; ++kt) {
            u16x8 pf = *(const u16x8*)&pw[l15 * PSTR + kt * 32 + lg * 8];
            #pragma unroll
            for (int dt = 0; dt < 4; ++dt) {
                const unsigned short* vp = &VT_lds[(dt * 16 + l15) * VSTR + kt * 32 + lg * 8];
                u16x4 va = *(const u16x4*)vp;
                u16x4 vb = *(const u16x4*)(vp + 4);
                u16x8 vf = __builtin_shufflevector(va, vb, 0, 1, 2, 3, 4, 5, 6, 7);
                o_acc[dt] = mfma_bf16(pf, vf, o_acc[dt]);
            }
        }
        __syncthreads();
    }

    // ---- epilogue: O / l -> out (fp32) ----
    const int orow0 = base + qbase + w * 16;
    #pragma unroll
    for (int r = 0; r < 4; ++r) {
        float inv = 1.0f / l_run[r];
        #pragma unroll
        for (int dt = 0; dt < 4; ++dt) {
            int row = orow0 + lg * 4 + r;
            out[row * DH + dt * 16 + l15] = o_acc[dt][r] * inv;
        }
    }
}

// ---------------------------------------------------------------------------
extern "C" void kernel_launch(void* const* d_in, const int* in_sizes, int n_in,
                              void* d_out, int out_size, void* d_ws, size_t ws_size,
                              hipStream_t stream)
{
    const float* x  = (const float*)d_in[0];
    const float* wq = (const float*)d_in[1];
    const float* wk = (const float*)d_in[2];
    const float* wv = (const float*)d_in[3];
    float* out = (float*)d_out;

    // ws layout: WT bf16 [3][64][128] @0 (48KB), then q/k/v bf16 [16384][64]
    unsigned short* wt = (unsigned short*)d_ws;
    unsigned short* qw = (unsigned short*)((char*)d_ws + 65536);
    unsigned short* kw = qw + 16384 * DH;
    unsigned short* vw = kw + 16384 * DH;

    prep_w_kernel<<<96, 256, 0, stream>>>(wq, wk, wv, wt);
    proj_kernel<<<256, 256, 0, stream>>>(x, wt, qw, kw, vw);
    attn_kernel<<<256, 256, 0, stream>>>(qw, kw, vw, out);
}

// Round 2
// 101.844 us; speedup vs baseline: 1.3336x; 1.3336x over previous
//
#include <hip/hip_runtime.h>
#include <hip/hip_bf16.h>

// ---------------------------------------------------------------------------
// Fused causal attention head: B=4, T=4096, E=128, D=64, fp32 in/out.
// prep_w (W -> WT bf16) -> proj (x@W MFMA, bf16 q/k/v in ws)
// -> attn_partial (split-KV flash, chunks of 512 keys, partials in ws)
// -> attn_combine (weighted merge of partials).
// Fallback to single-kernel flash if ws_size too small.
// ---------------------------------------------------------------------------

typedef __attribute__((ext_vector_type(4))) float  f32x4;
typedef __attribute__((ext_vector_type(8))) __bf16 bf16x8;
typedef __attribute__((ext_vector_type(8))) unsigned short u16x8;
typedef __attribute__((ext_vector_type(4))) unsigned short u16x4;

#define T_SEQ 4096
#define DH    64
#define EDIM  128
#define QB    64
#define KVB   64
#define NCH   8      // KV chunks per q-tile row range
#define CHUNK 512    // keys per chunk = 8 KVB tiles
#define KSTR  72
#define VSTR  76
#define PSTR  72

__device__ __forceinline__ unsigned short f2bf(float f) {
    unsigned int x = __builtin_bit_cast(unsigned int, f);
    unsigned int r = x + 0x7fffu + ((x >> 16) & 1u);
    return (unsigned short)(r >> 16);
}

__device__ __forceinline__ f32x4 mfma_bf16(u16x8 a, u16x8 b, f32x4 c) {
    return __builtin_amdgcn_mfma_f32_16x16x32_bf16(
        __builtin_bit_cast(bf16x8, a), __builtin_bit_cast(bf16x8, b), c, 0, 0, 0);
}

// --------------------------- prep_w -----------------------------------------
__global__ __launch_bounds__(256) void prep_w_kernel(
    const float* __restrict__ wq, const float* __restrict__ wk,
    const float* __restrict__ wv, unsigned short* __restrict__ wt)
{
    int o = blockIdx.x * 256 + threadIdx.x;
    int m   = o >> 13;
    int rem = o & 8191;
    int d = rem >> 7, e = rem & 127;
    const float* W = (m == 0) ? wq : (m == 1) ? wk : wv;
    wt[o] = f2bf(W[e * DH + d]);
}

// --------------------------- proj -------------------------------------------
__global__ __launch_bounds__(256) void proj_kernel(
    const float* __restrict__ x, const unsigned short* __restrict__ wt,
    unsigned short* __restrict__ qw, unsigned short* __restrict__ kw,
    unsigned short* __restrict__ vw)
{
    __shared__ unsigned short x_lds[64 * 136];

    const int tid = threadIdx.x;
    const int w   = tid >> 6;
    const int l   = tid & 63;
    const int l15 = l & 15;
    const int lg  = l >> 4;
    const int row0 = blockIdx.x * 64;

    #pragma unroll
    for (int i = 0; i < 8; ++i) {
        int f4  = tid + i * 256;
        int row = f4 >> 5;
        int c4  = (f4 & 31) * 4;
        f32x4 xv = *(const f32x4*)(x + (row0 + row) * EDIM + c4);
        u16x4 bv = { f2bf(xv[0]), f2bf(xv[1]), f2bf(xv[2]), f2bf(xv[3]) };
        *(u16x4*)&x_lds[row * 136 + c4] = bv;
    }
    __syncthreads();

    u16x8 af[4];
    #pragma unroll
    for (int kt = 0; kt < 4; ++kt)
        af[kt] = *(const u16x8*)&x_lds[(w * 16 + l15) * 136 + kt * 32 + lg * 8];

    unsigned short* outs[3] = { qw, kw, vw };
    #pragma unroll
    for (int m = 0; m < 3; ++m) {
        #pragma unroll
        for (int nt = 0; nt < 4; ++nt) {
            f32x4 acc = {};
            #pragma unroll
            for (int kt = 0; kt < 4; ++kt) {
                u16x8 bfrag = *(const u16x8*)(wt + (m * 64 + nt * 16 + l15) * EDIM
                                                 + kt * 32 + lg * 8);
                acc = mfma_bf16(af[kt], bfrag, acc);
            }
            const float sc = (m == 0) ? 0.125f : 1.0f;
            #pragma unroll
            for (int r = 0; r < 4; ++r) {
                int row = row0 + w * 16 + lg * 4 + r;
                outs[m][row * DH + nt * 16 + l15] = f2bf(acc[r] * sc);
            }
        }
    }
}

// --------------------------- flash inner loop (shared by both paths) --------
struct FlashState {
    f32x4 o_acc[4];
    float m_run[4], l_run[4];
};

__device__ __forceinline__ void flash_tiles(
    const unsigned short* __restrict__ kg, const unsigned short* __restrict__ vg,
    unsigned short* K_lds, unsigned short* VT_lds, unsigned short* P_lds,
    int base, int qbase, int kv_begin, int kv_end,
    const u16x8* qf, FlashState& st,
    int w, int l15, int lg, int tid)
{
    for (int kv0 = kv_begin; kv0 < kv_end; kv0 += KVB) {
        #pragma unroll
        for (int i = 0; i < 4; ++i) {
            int f4  = tid + i * 256;
            int row = f4 >> 4;
            int c4  = (f4 & 15) * 4;
            u16x4 kk = *(const u16x4*)(kg + (base + kv0 + row) * DH + c4);
            *(u16x4*)&K_lds[row * KSTR + c4] = kk;
            u16x4 vv = *(const u16x4*)(vg + (base + kv0 + row) * DH + c4);
            #pragma unroll
            for (int j = 0; j < 4; ++j)
                VT_lds[(c4 + j) * VSTR + row] = vv[j];
        }
        __syncthreads();

        f32x4 s[4];
        #pragma unroll
        for (int nt = 0; nt < 4; ++nt) {
            f32x4 acc = {};
            #pragma unroll
            for (int kt = 0; kt < 2; ++kt) {
                u16x8 kf = *(const u16x8*)&K_lds[(nt * 16 + l15) * KSTR + kt * 32 + lg * 8];
                acc = mfma_bf16(qf[kt], kf, acc);
            }
            s[nt] = acc;
        }

        if (kv0 == qbase) {   // diagonal tile: causal mask
            #pragma unroll
            for (int nt = 0; nt < 4; ++nt)
                #pragma unroll
                for (int r = 0; r < 4; ++r) {
                    int qi = w * 16 + lg * 4 + r;          // within tile
                    int kj = nt * 16 + l15;
                    if (kj > qi) s[nt][r] = -1e30f;
                }
        }

        #pragma unroll
        for (int r = 0; r < 4; ++r) {
            float m0 = fmaxf(fmaxf(s[0][r], s[1][r]), fmaxf(s[2][r], s[3][r]));
            m0 = fmaxf(m0, __shfl_xor(m0, 1));
            m0 = fmaxf(m0, __shfl_xor(m0, 2));
            m0 = fmaxf(m0, __shfl_xor(m0, 4));
            m0 = fmaxf(m0, __shfl_xor(m0, 8));

            float mnew  = fmaxf(st.m_run[r], m0);
            float scale = __expf(st.m_run[r] - mnew);
            st.m_run[r] = mnew;
            st.l_run[r] *= scale;
            #pragma unroll
            for (int dt = 0; dt < 4; ++dt) st.o_acc[dt][r] *= scale;

            float rs = 0.0f;
            #pragma unroll
            for (int nt = 0; nt < 4; ++nt) {
                float p0 = __expf(s[nt][r] - mnew);
                s[nt][r] = p0;
                rs += p0;
            }
            rs += __shfl_xor(rs, 1);
            rs += __shfl_xor(rs, 2);
            rs += __shfl_xor(rs, 4);
            rs += __shfl_xor(rs, 8);
            st.l_run[r] += rs;
        }

        unsigned short* pw = &P_lds[w * 16 * PSTR];
        #pragma unroll
        for (int nt = 0; nt < 4; ++nt)
            #pragma unroll
            for (int r = 0; r < 4; ++r)
                pw[(lg * 4 + r) * PSTR + nt * 16 + l15] = f2bf(s[nt][r]);

        #pragma unroll
        for (int kt = 0; kt < 2; ++kt) {
            u16x8 pf = *(const u16x8*)&pw[l15 * PSTR + kt * 32 + lg * 8];
            #pragma unroll
            for (int dt = 0; dt < 4; ++dt) {
                const unsigned short* vp = &VT_lds[(dt * 16 + l15) * VSTR + kt * 32 + lg * 8];
                u16x4 va = *(const u16x4*)vp;
                u16x4 vb = *(const u16x4*)(vp + 4);
                u16x8 vf = __builtin_shufflevector(va, vb, 0, 1, 2, 3, 4, 5, 6, 7);
                st.o_acc[dt] = mfma_bf16(pf, vf, st.o_acc[dt]);
            }
        }
        __syncthreads();
    }
}

// --------------------------- phase 1: split-KV partials ---------------------
__global__ __launch_bounds__(256) void attn_partial_kernel(
    const unsigned short* __restrict__ qg, const unsigned short* __restrict__ kg,
    const unsigned short* __restrict__ vg,
    float* __restrict__ po, float* __restrict__ pm, float* __restrict__ pl)
{
    const int bid = blockIdx.x;          // (b*64 + qt)*8 + ch
    const int ch  = bid & (NCH - 1);
    const int qt  = (bid >> 3) & 63;
    const int b   = bid >> 9;
    if (ch * 8 > qt) return;             // beyond causal range

    __shared__ unsigned short K_lds[KVB * KSTR];
    __shared__ unsigned short VT_lds[DH * VSTR];
    __shared__ unsigned short P_lds[4 * 16 * PSTR];

    const int tid = threadIdx.x;
    const int w   = tid >> 6;
    const int l   = tid & 63;
    const int l15 = l & 15;
    const int lg  = l >> 4;

    const int qbase = qt * QB;
    const int base  = b * T_SEQ;
    const int kv_begin = ch * CHUNK;
    const int kv_end   = min(kv_begin + CHUNK, qbase + QB);

    u16x8 qf[2];
    {
        const unsigned short* qrow = qg + (base + qbase + w * 16 + l15) * DH;
        qf[0] = *(const u16x8*)(qrow +  0 + lg * 8);
        qf[1] = *(const u16x8*)(qrow + 32 + lg * 8);
    }

    FlashState st;
    #pragma unroll
    for (int dt = 0; dt < 4; ++dt) st.o_acc[dt] = f32x4{};
    #pragma unroll
    for (int r = 0; r < 4; ++r) { st.m_run[r] = -1e30f; st.l_run[r] = 0.0f; }

    flash_tiles(kg, vg, K_lds, VT_lds, P_lds, base, qbase, kv_begin, kv_end,
                qf, st, w, l15, lg, tid);

    // write partials
    const int pidx = (b * 64 + qt) * NCH + ch;
    float* pob = po + pidx * (QB * DH);
    #pragma unroll
    for (int r = 0; r < 4; ++r) {
        int row = w * 16 + lg * 4 + r;
        #pragma unroll
        for (int dt = 0; dt < 4; ++dt)
            pob[row * DH + dt * 16 + l15] = st.o_acc[dt][r];
        if (l15 == 0) {
            pm[pidx * QB + row] = st.m_run[r];
            pl[pidx * QB + row] = st.l_run[r];
        }
    }
}

// --------------------------- phase 2: combine -------------------------------
__global__ __launch_bounds__(256) void attn_combine_kernel(
    const float* __restrict__ po, const float* __restrict__ pm,
    const float* __restrict__ pl, float* __restrict__ out)
{
    const int tb  = blockIdx.x;          // b*64 + qt
    const int qt  = tb & 63;
    const int nch = (qt >> 3) + 1;
    const int row = threadIdx.x >> 2;
    const int dq  = (threadIdx.x & 3) * 16;
    const int base_p = tb * NCH;

    float mstar = -1e30f;
    float m_i[NCH];
    #pragma unroll
    for (int i = 0; i < NCH; ++i) {
        if (i < nch) {
            m_i[i] = pm[(base_p + i) * QB + row];
            mstar = fmaxf(mstar, m_i[i]);
        }
    }
    float w_i[NCH];
    float lsum = 0.0f;
    #pragma unroll
    for (int i = 0; i < NCH; ++i) {
        if (i < nch) {
            w_i[i] = __expf(m_i[i] - mstar);
            lsum += w_i[i] * pl[(base_p + i) * QB + row];
        }
    }
    const float inv = 1.0f / lsum;

    f32x4 acc[4] = {};
    #pragma unroll
    for (int i = 0; i < NCH; ++i) {
        if (i < nch) {
            const float* p = po + (base_p + i) * (QB * DH) + row * DH + dq;
            #pragma unroll
            for (int j = 0; j < 4; ++j) {
                f32x4 v = *(const f32x4*)(p + j * 4);
                acc[j] += w_i[i] * v;
            }
        }
    }
    float* o = out + (tb * QB + row) * DH + dq;
    #pragma unroll
    for (int j = 0; j < 4; ++j)
        *(f32x4*)(o + j * 4) = acc[j] * inv;
}

// --------------------------- fallback: single-kernel flash ------------------
__global__ __launch_bounds__(256) void attn_kernel(
    const unsigned short* __restrict__ qg, const unsigned short* __restrict__ kg,
    const unsigned short* __restrict__ vg, float* __restrict__ out)
{
    __shared__ unsigned short K_lds[KVB * KSTR];
    __shared__ unsigned short VT_lds[DH * VSTR];
    __shared__ unsigned short P_lds[4 * 16 * PSTR];

    const int tid = threadIdx.x;
    const int w   = tid >> 6;
    const int l   = tid & 63;
    const int l15 = l & 15;
    const int lg  = l >> 4;

    const int bid   = blockIdx.x;
    const int b     = bid >> 6;
    const int qt    = bid & 63;
    const int qbase = qt * QB;
    const int base  = b * T_SEQ;

    u16x8 qf[2];
    {
        const unsigned short* qrow = qg + (base + qbase + w * 16 + l15) * DH;
        qf[0] = *(const u16x8*)(qrow +  0 + lg * 8);
        qf[1] = *(const u16x8*)(qrow + 32 + lg * 8);
    }

    FlashState st;
    #pragma unroll
    for (int dt = 0; dt < 4; ++dt) st.o_acc[dt] = f32x4{};
    #pragma unroll
    for (int r = 0; r < 4; ++r) { st.m_run[r] = -1e30f; st.l_run[r] = 0.0f; }

    flash_tiles(kg, vg, K_lds, VT_lds, P_lds, base, qbase, 0, qbase + QB,
                qf, st, w, l15, lg, tid);

    const int orow0 = base + qbase + w * 16;
    #pragma unroll
    for (int r = 0; r < 4; ++r) {
        float inv = 1.0f / st.l_run[r];
        #pragma unroll
        for (int dt = 0; dt < 4; ++dt) {
            int row = orow0 + lg * 4 + r;
            out[row * DH + dt * 16 + l15] = st.o_acc[dt][r] * inv;
        }
    }
}

// ---------------------------------------------------------------------------
extern "C" void kernel_launch(void* const* d_in, const int* in_sizes, int n_in,
                              void* d_out, int out_size, void* d_ws, size_t ws_size,
                              hipStream_t stream)
{
    const float* x  = (const float*)d_in[0];
    const float* wq = (const float*)d_in[1];
    const float* wk = (const float*)d_in[2];
    const float* wv = (const float*)d_in[3];
    float* out = (float*)d_out;

    // ws layout:
    //   wt  bf16 [3][64][128]            @ 0        (64 KB reserved)
    //   qw/kw/vw bf16 [16384][64]        @ 64 KB    (2 MB each)
    //   po  f32 [2048][64][64]           @ 6356992  (32 MB)
    //   pm  f32 [2048][64]               @ 39911424 (512 KB)
    //   pl  f32 [2048][64]               @ 40435712 (512 KB)
    unsigned short* wt = (unsigned short*)d_ws;
    unsigned short* qw = (unsigned short*)((char*)d_ws + 65536);
    unsigned short* kw = qw + 16384 * DH;
    unsigned short* vw = kw + 16384 * DH;

    const size_t po_off = 65536u + 3u * 16384u * DH * 2u;
    const size_t po_sz  = (size_t)2048 * QB * DH * 4;
    const size_t pm_off = po_off + po_sz;
    const size_t pl_off = pm_off + (size_t)2048 * QB * 4;
    const size_t need   = pl_off + (size_t)2048 * QB * 4;

    prep_w_kernel<<<96, 256, 0, stream>>>(wq, wk, wv, wt);
    proj_kernel<<<256, 256, 0, stream>>>(x, wt, qw, kw, vw);

    if (ws_size >= need) {
        float* po = (float*)((char*)d_ws + po_off);
        float* pm = (float*)((char*)d_ws + pm_off);
        float* pl = (float*)((char*)d_ws + pl_off);
        attn_partial_kernel<<<4 * 64 * NCH, 256, 0, stream>>>(qw, kw, vw, po, pm, pl);
        attn_combine_kernel<<<256, 256, 0, stream>>>(po, pm, pl, out);
    } else {
        attn_kernel<<<256, 256, 0, stream>>>(qw, kw, vw, out);
    }
}